// Round 15
// baseline (306.757 us; speedup 1.0000x reference)
//
#include <hip/hip_runtime.h>
#include <hip/hip_fp16.h>
#include <math.h>

#define N_NODES 50000
#define N_EDGES 800000
#define D 64
#define NB 196            // dst buckets of 256 nodes (b = dst>>8)
#define CAP_B 6144        // per-bucket binned capacity (mean 4082, +32 sigma)
#define SLOT_CAP 64       // per-node CSR slot capacity (mean deg 16)
#define EB 2048           // edges per binA block (8 per thread)
#define BINA_BLOCKS ((N_EDGES + EB - 1) / EB)   // 391
#define GEMM_BLOCKS ((N_NODES + 63) / 64)       // 782
#define PLANE_HALVES ((size_t)N_NODES * 32)     // one 32-feature plane (3.2 MB)

// ---------------------------------------------------------------------------
// zero the 196 bucket cursors
// ---------------------------------------------------------------------------
__global__ void k_zero(int* __restrict__ bcur) {
    int t = threadIdx.x;
    if (t < NB) bcur[t] = 0;
}

// ---------------------------------------------------------------------------
// Pass A: bin edges by dst>>8 into 196 buckets. Entry PACKED to 4B:
// (src<<8)|(dst&255). Unchanged from R12 (passed).
// ---------------------------------------------------------------------------
__global__ __launch_bounds__(256) void k_binA(const int* __restrict__ src,
                                              const int* __restrict__ dst,
                                              int* __restrict__ bcur,
                                              unsigned* __restrict__ binned) {
    __shared__ int hist[NB];
    __shared__ int base[NB];
    int tid = threadIdx.x;
    int e0 = blockIdx.x * EB;

    unsigned pk[8];
    int eb[8];
    bool ev[8];
    #pragma unroll
    for (int k = 0; k < 8; ++k) {
        int e = e0 + k * 256 + tid;
        ev[k] = (e < N_EDGES);
        int s = ev[k] ? src[e] : 0;
        int d = ev[k] ? dst[e] : 0;
        eb[k] = d >> 8;
        pk[k] = ((unsigned)s << 8) | (unsigned)(d & 255);
    }
    if (tid < NB) hist[tid] = 0;
    __syncthreads();
    #pragma unroll
    for (int k = 0; k < 8; ++k) if (ev[k]) atomicAdd(&hist[eb[k]], 1);
    __syncthreads();
    if (tid < NB) {
        base[tid] = atomicAdd(&bcur[tid], hist[tid]);
        hist[tid] = 0;                      // reuse as rank counter
    }
    __syncthreads();
    #pragma unroll
    for (int k = 0; k < 8; ++k) {
        if (ev[k]) {
            int r = atomicAdd(&hist[eb[k]], 1);
            int pos = base[eb[k]] + r;
            if (pos < CAP_B)
                binned[(size_t)eb[k] * CAP_B + pos] = pk[k];
        }
    }
}

// ---------------------------------------------------------------------------
// Pass B: one block per bucket, LDS cursors, 64KB L2-resident csr window.
// Final cursor value IS the in-degree. Unchanged from R12 (passed).
// ---------------------------------------------------------------------------
__global__ __launch_bounds__(256) void k_binB(const int* __restrict__ bcur,
                                              const unsigned* __restrict__ binned,
                                              int* __restrict__ csr,
                                              int* __restrict__ cnt) {
    __shared__ int cur[256];
    int b = blockIdx.x;
    int tid = threadIdx.x;
    cur[tid] = 0;
    __syncthreads();
    int bn = bcur[b];
    if (bn > CAP_B) bn = CAP_B;
    const unsigned* bp = binned + (size_t)b * CAP_B;
    for (int i = tid; i < bn; i += 256) {
        unsigned e = bp[i];
        int dl = (int)(e & 255u);
        int s  = (int)(e >> 8);
        int c = atomicAdd(&cur[dl], 1);
        if (c < SLOT_CAP) {
            int node = (b << 8) + dl;
            csr[((size_t)node << 6) + c] = s;
        }
    }
    __syncthreads();
    int node = (b << 8) + tid;
    if (node < N_NODES) {
        int c = cur[tid];
        cnt[node] = (c > SLOT_CAP) ? SLOT_CAP : c;
    }
}

// ---------------------------------------------------------------------------
// GEMM: hWs[row,:] = (h[row,:] @ W) * rsqrt(cnt[row]+1), fp16 out, written
// into TWO FEATURE PLANES of 32 cols (plane = c0>>5) so each gather pass
// touches a 3.2MB L2-resident slice. Compute core unchanged from R12.
// ---------------------------------------------------------------------------
__global__ __launch_bounds__(256) void k_gemm(const float* __restrict__ h, int hstride,
                                              const float* __restrict__ W,
                                              const int* __restrict__ cnt,
                                              __half* __restrict__ hWh) {
    __shared__ float Ws[64][64];          // 16 KB
    __shared__ __half2 hs2[64 * 34];      // 8.7 KB, row stride 34 half2
    int tid = threadIdx.x;
    int row0 = blockIdx.x * 64;

    const float4* W4 = (const float4*)W;
    for (int i = tid; i < 64 * 16; i += 256) {
        float4 w = W4[i];
        *(float4*)&Ws[i >> 4][(i & 15) << 2] = w;
    }
    for (int i = tid; i < 64 * 16; i += 256) {
        int r = i >> 4, c4 = (i & 15) << 2;
        int gr = row0 + r;
        float4 hv = make_float4(0.f, 0.f, 0.f, 0.f);
        if (gr < N_NODES) hv = *(const float4*)&h[(size_t)gr * hstride + c4];
        __half2 p01 = __floats2half2_rn(hv.x, hv.y);
        __half2 p23 = __floats2half2_rn(hv.z, hv.w);
        uint2 st;
        st.x = *(unsigned*)&p01;
        st.y = *(unsigned*)&p23;
        *(uint2*)&hs2[r * 34 + (c4 >> 1)] = st;
    }
    __syncthreads();

    int c0 = (tid & 15) << 2;    // output cols c0..c0+3
    int r0 = (tid >> 4) << 2;    // output rows r0..r0+3
    float4 a0 = make_float4(0.f, 0.f, 0.f, 0.f);
    float4 a1 = a0, a2 = a0, a3 = a0;

    #pragma unroll 2
    for (int k0 = 0; k0 < 64; k0 += 4) {
        float4 w0 = *(const float4*)&Ws[k0 + 0][c0];
        float4 w1 = *(const float4*)&Ws[k0 + 1][c0];
        float4 w2 = *(const float4*)&Ws[k0 + 2][c0];
        float4 w3 = *(const float4*)&Ws[k0 + 3][c0];
#define LOAD_H(i, HV)                                                   \
        float4 HV;                                                      \
        {                                                               \
            uint2 hp = *(const uint2*)&hs2[(r0 + i) * 34 + (k0 >> 1)];  \
            float2 f01 = __half22float2(*(const __half2*)&hp.x);        \
            float2 f23 = __half22float2(*(const __half2*)&hp.y);        \
            HV = make_float4(f01.x, f01.y, f23.x, f23.y);               \
        }
        LOAD_H(0, h0)
        LOAD_H(1, h1)
        LOAD_H(2, h2)
        LOAD_H(3, h3)
#undef LOAD_H
#define GEMM_ROW(A, H)                                            \
        A.x += H.x*w0.x + H.y*w1.x + H.z*w2.x + H.w*w3.x;         \
        A.y += H.x*w0.y + H.y*w1.y + H.z*w2.y + H.w*w3.y;         \
        A.z += H.x*w0.z + H.y*w1.z + H.z*w2.z + H.w*w3.z;         \
        A.w += H.x*w0.w + H.y*w1.w + H.z*w2.w + H.w*w3.w;
        GEMM_ROW(a0, h0)
        GEMM_ROW(a1, h1)
        GEMM_ROW(a2, h2)
        GEMM_ROW(a3, h3)
#undef GEMM_ROW
    }

    int plane = c0 >> 5;
    int cc = c0 & 31;
    uint2* dstp = (uint2*)(hWh + (size_t)plane * PLANE_HALVES);
    #pragma unroll
    for (int i = 0; i < 4; ++i) {
        int gr = row0 + r0 + i;
        if (gr < N_NODES) {
            float4 v = (i == 0) ? a0 : (i == 1) ? a1 : (i == 2) ? a2 : a3;
            float dn = rsqrtf((float)cnt[gr] + 1.0f);
            __half2 p01 = __floats2half2_rn(v.x * dn, v.y * dn);
            __half2 p23 = __floats2half2_rn(v.z * dn, v.w * dn);
            uint2 st;
            st.x = *(unsigned*)&p01;
            st.y = *(unsigned*)&p23;
            dstp[((size_t)gr << 3) + (cc >> 2)] = st;
        }
    }
}

// ---------------------------------------------------------------------------
// Gather v6 (half-feature pass): wave per node over ONE 32-feature plane
// (3.2MB, fits each XCD's 4MB L2 -> random reads become L2 hits; R13
// post-mortem: gather was L2-miss-bound, not issue-bound). Lane=(g 0..15,
// fo 0..3): 16 edges per uint4 VMEM instr. Wave-uniform shfl (R10 lesson).
// ---------------------------------------------------------------------------
__global__ __launch_bounds__(256) void k_gather(const uint4* __restrict__ hWp,  // [N][4]
                                                const int* __restrict__ csr,
                                                const int* __restrict__ cnt,
                                                const float* __restrict__ bias,  // 32 floats
                                                float* __restrict__ out, int col_off) {
    int gid = blockIdx.x * blockDim.x + threadIdx.x;
    int node = gid >> 6;
    if (node >= N_NODES) return;
    int lane = threadIdx.x & 63;
    int fo = lane & 3;           // uint4 (8 features) within the 32-col plane
    int g  = lane >> 2;          // edge group 0..15
    int n = cnt[node];           // wave-uniform
    const int* row = csr + ((size_t)node << 6);

    int myidx = (lane < n) ? row[lane] : 0;      // whole row, one coalesced load

    float4 aA = make_float4(0.f, 0.f, 0.f, 0.f);
    float4 aB = aA;
#define ACC8(V)                                                      \
    {                                                                \
        float2 f0 = __half22float2(*(const __half2*)&(V).x);         \
        float2 f1 = __half22float2(*(const __half2*)&(V).y);         \
        float2 f2 = __half22float2(*(const __half2*)&(V).z);         \
        float2 f3 = __half22float2(*(const __half2*)&(V).w);         \
        aA.x += f0.x; aA.y += f0.y; aA.z += f1.x; aA.w += f1.y;      \
        aB.x += f2.x; aB.y += f2.y; aB.z += f3.x; aB.w += f3.y;      \
    }
    int nFull = n >> 4;          // full 16-edge iterations (wave-uniform, <=4)
    int tail  = n & 15;
    int it = 0;
    for (; it + 1 < nFull; it += 2) {            // 2 x 16B loads in flight
        int s0 = __shfl(myidx, (it << 4) + g, 64);
        int s1 = __shfl(myidx, ((it + 1) << 4) + g, 64);
        uint4 v0 = hWp[((size_t)s0 << 2) + fo];
        uint4 v1 = hWp[((size_t)s1 << 2) + fo];
        ACC8(v0)
        ACC8(v1)
    }
    if (it < nFull) {
        int s0 = __shfl(myidx, (it << 4) + g, 64);
        uint4 v0 = hWp[((size_t)s0 << 2) + fo];
        ACC8(v0)
    }
    if (tail) {                                   // wave-uniform branch
        int s0 = __shfl(myidx, (nFull << 4) + g, 64);   // all lanes active
        if (g < tail) {
            uint4 v0 = hWp[((size_t)s0 << 2) + fo];
            ACC8(v0)
        }
    }
#undef ACC8

    // combine the 16 edge-groups (lane bits 2..5)
    #pragma unroll
    for (int off = 4; off <= 32; off <<= 1) {
        aA.x += __shfl_xor(aA.x, off, 64);
        aA.y += __shfl_xor(aA.y, off, 64);
        aA.z += __shfl_xor(aA.z, off, 64);
        aA.w += __shfl_xor(aA.w, off, 64);
        aB.x += __shfl_xor(aB.x, off, 64);
        aB.y += __shfl_xor(aB.y, off, 64);
        aB.z += __shfl_xor(aB.z, off, 64);
        aB.w += __shfl_xor(aB.w, off, 64);
    }

    if (g == 0) {                // lanes 0..3 hold the full sums
        uint4 sv = hWp[((size_t)node << 2) + fo];
        float2 s0 = __half22float2(*(const __half2*)&sv.x);
        float2 s1 = __half22float2(*(const __half2*)&sv.y);
        float2 s2 = __half22float2(*(const __half2*)&sv.z);
        float2 s3 = __half22float2(*(const __half2*)&sv.w);
        float dn = rsqrtf((float)n + 1.0f);
        float4 b0 = *(const float4*)&bias[(fo << 3) + 0];
        float4 b1 = *(const float4*)&bias[(fo << 3) + 4];
        float o0 = b0.x + dn * (s0.x + aA.x);
        float o1 = b0.y + dn * (s0.y + aA.y);
        float o2 = b0.z + dn * (s1.x + aA.z);
        float o3 = b0.w + dn * (s1.y + aA.w);
        float o4 = b1.x + dn * (s2.x + aB.x);
        float o5 = b1.y + dn * (s2.y + aB.y);
        float o6 = b1.z + dn * (s3.x + aB.z);
        float o7 = b1.w + dn * (s3.y + aB.w);
        o0 = (o0 > 0.f) ? o0 : expm1f(o0);
        o1 = (o1 > 0.f) ? o1 : expm1f(o1);
        o2 = (o2 > 0.f) ? o2 : expm1f(o2);
        o3 = (o3 > 0.f) ? o3 : expm1f(o3);
        o4 = (o4 > 0.f) ? o4 : expm1f(o4);
        o5 = (o5 > 0.f) ? o5 : expm1f(o5);
        o6 = (o6 > 0.f) ? o6 : expm1f(o6);
        o7 = (o7 > 0.f) ? o7 : expm1f(o7);
        float* op = &out[(size_t)node * (3 * D) + col_off + (fo << 3)];
        *(float4*)&op[0] = make_float4(o0, o1, o2, o3);
        *(float4*)&op[4] = make_float4(o4, o5, o6, o7);
    }
}

extern "C" void kernel_launch(void* const* d_in, const int* in_sizes, int n_in,
                              void* d_out, int out_size, void* d_ws, size_t ws_size,
                              hipStream_t stream) {
    const float* x   = (const float*)d_in[0];
    const int*   ei  = (const int*)d_in[1];
    const int*   src = ei;
    const int*   dst = ei + N_EDGES;
    const float* W[3] = {(const float*)d_in[2], (const float*)d_in[4], (const float*)d_in[6]};
    const float* b[3] = {(const float*)d_in[3], (const float*)d_in[5], (const float*)d_in[7]};
    float* out = (float*)d_out;

    // workspace layout (hWh 16B-aligned for uint4 reads)
    char* ws = (char*)d_ws;
    unsigned* binned = (unsigned*)ws;            ws += (size_t)NB * CAP_B * 4;
    int*    bcur   = (int*)ws;                   ws += 256 * 4;
    int*    cnt    = (int*)ws;                   ws += N_NODES * 4;
    int*    csr    = (int*)ws;                   ws += (size_t)N_NODES * SLOT_CAP * 4;
    __half* hWh    = (__half*)ws;                // 2 planes x N*32 halves

    // CSR build: zero cursors, bin, scatter-within-bucket
    k_zero<<<1, 256, 0, stream>>>(bcur);
    k_binA<<<BINA_BLOCKS, 256, 0, stream>>>(src, dst, bcur, binned);
    k_binB<<<NB, 256, 0, stream>>>(bcur, binned, csr, cnt);

    long long gthreads = (long long)N_NODES * 64;
    int gather_grid = (int)((gthreads + 255) / 256);   // 12500

    const float* hin = x;
    int hstride = D;
    for (int l = 0; l < 3; ++l) {
        k_gemm<<<GEMM_BLOCKS, 256, 0, stream>>>(hin, hstride, W[l], cnt, hWh);
        // two half-feature passes; separate launches keep each 3.2MB plane
        // L2-resident on every XCD (concurrent passes would double the set)
        for (int p = 0; p < 2; ++p) {
            k_gather<<<gather_grid, 256, 0, stream>>>(
                (const uint4*)(hWh + (size_t)p * PLANE_HALVES), csr, cnt,
                b[l] + p * 32, out, l * D + p * 32);
        }
        hin = out + l * D;
        hstride = 3 * D;
    }
}

// Round 16
// 240.601 us; speedup vs baseline: 1.2750x; 1.2750x over previous
//
#include <hip/hip_runtime.h>
#include <hip/hip_fp16.h>
#include <math.h>

#define N_NODES 50000
#define N_EDGES 800000
#define D 64
#define NB 196            // dst buckets of 256 nodes (b = dst>>8)
#define CAP_B 6144        // per-bucket binned capacity (mean 4082, +32 sigma)
#define SLOT_CAP 64       // per-node CSR slot capacity (mean deg 16)
#define EB 2048           // edges per binA block (8 per thread)
#define BINA_BLOCKS ((N_EDGES + EB - 1) / EB)   // 391
#define LAYER_BLOCKS 2048                       // 8 blocks/CU, full occupancy

// ---------------------------------------------------------------------------
// zero the 196 bucket cursors
// ---------------------------------------------------------------------------
__global__ void k_zero(int* __restrict__ bcur) {
    int t = threadIdx.x;
    if (t < NB) bcur[t] = 0;
}

// ---------------------------------------------------------------------------
// Pass A: bin edges by dst>>8 into 196 buckets. Entry packed to 4B:
// (src<<8)|(dst&255). Unchanged since R12 (passed).
// ---------------------------------------------------------------------------
__global__ __launch_bounds__(256) void k_binA(const int* __restrict__ src,
                                              const int* __restrict__ dst,
                                              int* __restrict__ bcur,
                                              unsigned* __restrict__ binned) {
    __shared__ int hist[NB];
    __shared__ int base[NB];
    int tid = threadIdx.x;
    int e0 = blockIdx.x * EB;

    unsigned pk[8];
    int eb[8];
    bool ev[8];
    #pragma unroll
    for (int k = 0; k < 8; ++k) {
        int e = e0 + k * 256 + tid;
        ev[k] = (e < N_EDGES);
        int s = ev[k] ? src[e] : 0;
        int d = ev[k] ? dst[e] : 0;
        eb[k] = d >> 8;
        pk[k] = ((unsigned)s << 8) | (unsigned)(d & 255);
    }
    if (tid < NB) hist[tid] = 0;
    __syncthreads();
    #pragma unroll
    for (int k = 0; k < 8; ++k) if (ev[k]) atomicAdd(&hist[eb[k]], 1);
    __syncthreads();
    if (tid < NB) {
        base[tid] = atomicAdd(&bcur[tid], hist[tid]);
        hist[tid] = 0;                      // reuse as rank counter
    }
    __syncthreads();
    #pragma unroll
    for (int k = 0; k < 8; ++k) {
        if (ev[k]) {
            int r = atomicAdd(&hist[eb[k]], 1);
            int pos = base[eb[k]] + r;
            if (pos < CAP_B)
                binned[(size_t)eb[k] * CAP_B + pos] = pk[k];
        }
    }
}

// ---------------------------------------------------------------------------
// Pass B: one block per bucket, LDS cursors, L2-resident csr window; ALSO
// packs this bucket's first-layer messages m0 = dinv * x (fp16) — the block
// owns exactly these 256 nodes and just computed their degrees.
// ---------------------------------------------------------------------------
__global__ __launch_bounds__(256) void k_binB(const int* __restrict__ bcur,
                                              const unsigned* __restrict__ binned,
                                              int* __restrict__ csr,
                                              int* __restrict__ cnt,
                                              const float* __restrict__ x,
                                              __half* __restrict__ m0) {
    __shared__ int cur[256];
    __shared__ float dinvS[256];
    int b = blockIdx.x;
    int tid = threadIdx.x;
    cur[tid] = 0;
    __syncthreads();
    int bn = bcur[b];
    if (bn > CAP_B) bn = CAP_B;
    const unsigned* bp = binned + (size_t)b * CAP_B;
    for (int i = tid; i < bn; i += 256) {
        unsigned e = bp[i];
        int dl = (int)(e & 255u);
        int s  = (int)(e >> 8);
        int c = atomicAdd(&cur[dl], 1);
        if (c < SLOT_CAP) {
            int node = (b << 8) + dl;
            csr[((size_t)node << 6) + c] = s;
        }
    }
    __syncthreads();
    int node = (b << 8) + tid;
    int myc = 0;
    if (node < N_NODES) {
        int c = cur[tid];
        myc = (c > SLOT_CAP) ? SLOT_CAP : c;
        cnt[node] = myc;
    }
    dinvS[tid] = rsqrtf((float)myc + 1.0f);
    __syncthreads();
    int base = b << 8;
    for (int i = tid; i < 256 * 16; i += 256) {
        int nl = i >> 4, c4 = (i & 15) << 2;
        int gn = base + nl;
        if (gn < N_NODES) {
            float4 hv = *(const float4*)&x[((size_t)gn << 6) + c4];
            float dv = dinvS[nl];
            __half2 p01 = __floats2half2_rn(hv.x * dv, hv.y * dv);
            __half2 p23 = __floats2half2_rn(hv.z * dv, hv.w * dv);
            uint2 st;
            st.x = *(unsigned*)&p01;
            st.y = *(unsigned*)&p23;
            *(uint2*)&m0[((size_t)gn << 6) + c4] = st;
        }
    }
}

// ---------------------------------------------------------------------------
// Fused layer: Agg(h)W = Agg(hW) (linearity) -> gather FIRST (R13's proven
// inner loop over fp16 messages), transform AFTER, one kernel per layer.
// Wave per node (grid-stride): gather edge-sum into wave-private LDS slice,
// then 64 lanes compute out[col] = b + dn*sum_k agg[k]*Ws[k][col], ELU,
// write fp32 concat row + next layer's fp16 message row (dn*elu).
// Kills the 3 GEMM kernels + hW round-trip; 6 launches total (was 9/12).
// No __syncthreads in node loop: aggS is wave-private; sched_barrier(0)
// pins compile-time order of the LDS handoff.
// ---------------------------------------------------------------------------
__global__ __launch_bounds__(256) void k_layer(const uint4* __restrict__ mprev, // [N][8]
                                               const int* __restrict__ csr,
                                               const int* __restrict__ cnt,
                                               const float* __restrict__ W,
                                               const float* __restrict__ bias,
                                               float* __restrict__ out, int col_off,
                                               __half* __restrict__ mnext,
                                               int write_next) {
    __shared__ float Ws[64][64];     // 16 KB
    __shared__ float aggS[4][64];    // wave-private slices
    int tid = threadIdx.x;

    const float4* W4 = (const float4*)W;
    for (int i = tid; i < 1024; i += 256)
        *(float4*)&Ws[i >> 4][(i & 15) << 2] = W4[i];
    __syncthreads();

    int lane = tid & 63;
    int w = tid >> 6;
    int fo = lane & 7;               // feature octet (uint4) 0..7
    int g  = lane >> 3;              // edge group 0..7
    float bcol = bias[lane];
    int wave_id = blockIdx.x * 4 + w;
    int nwaves = LAYER_BLOCKS * 4;

    for (int node = wave_id; node < N_NODES; node += nwaves) {
        int n = cnt[node];           // wave-uniform
        const int* row = csr + ((size_t)node << 6);
        int myidx = (lane < n) ? row[lane] : 0;   // whole CSR row, one load

        float4 aA = make_float4(0.f, 0.f, 0.f, 0.f);
        float4 aB = aA;
#define ACC8(V)                                                      \
        {                                                            \
            float2 f0 = __half22float2(*(const __half2*)&(V).x);     \
            float2 f1 = __half22float2(*(const __half2*)&(V).y);     \
            float2 f2 = __half22float2(*(const __half2*)&(V).z);     \
            float2 f3 = __half22float2(*(const __half2*)&(V).w);     \
            aA.x += f0.x; aA.y += f0.y; aA.z += f1.x; aA.w += f1.y;  \
            aB.x += f2.x; aB.y += f2.y; aB.z += f3.x; aB.w += f3.y;  \
        }
        int nFull = n >> 3;          // wave-uniform
        int tail  = n & 7;
        int it = 0;
        for (; it + 1 < nFull; it += 2) {        // 2 x 16B loads in flight
            int s0 = __shfl(myidx, (it << 3) + g, 64);
            int s1 = __shfl(myidx, ((it + 1) << 3) + g, 64);
            uint4 v0 = mprev[((size_t)s0 << 3) + fo];
            uint4 v1 = mprev[((size_t)s1 << 3) + fo];
            ACC8(v0)
            ACC8(v1)
        }
        if (it < nFull) {
            int s0 = __shfl(myidx, (it << 3) + g, 64);
            uint4 v0 = mprev[((size_t)s0 << 3) + fo];
            ACC8(v0)
        }
        if (tail) {                               // wave-uniform branch
            int s0 = __shfl(myidx, (nFull << 3) + g, 64);  // all lanes active
            if (g < tail) {
                uint4 v0 = mprev[((size_t)s0 << 3) + fo];
                ACC8(v0)
            }
        }
#undef ACC8
        // reduce the 8 edge-groups (lane bits 3..5)
        #pragma unroll
        for (int off = 8; off <= 32; off <<= 1) {
            aA.x += __shfl_xor(aA.x, off, 64);
            aA.y += __shfl_xor(aA.y, off, 64);
            aA.z += __shfl_xor(aA.z, off, 64);
            aA.w += __shfl_xor(aA.w, off, 64);
            aB.x += __shfl_xor(aB.x, off, 64);
            aB.y += __shfl_xor(aB.y, off, 64);
            aB.z += __shfl_xor(aB.z, off, 64);
            aB.w += __shfl_xor(aB.w, off, 64);
        }
        if (g == 0) {                // lanes 0..7: add self message, park in LDS
            uint4 sv = mprev[((size_t)node << 3) + fo];
            float2 s0 = __half22float2(*(const __half2*)&sv.x);
            float2 s1 = __half22float2(*(const __half2*)&sv.y);
            float2 s2 = __half22float2(*(const __half2*)&sv.z);
            float2 s3 = __half22float2(*(const __half2*)&sv.w);
            aA.x += s0.x; aA.y += s0.y; aA.z += s1.x; aA.w += s1.y;
            aB.x += s2.x; aB.y += s2.y; aB.z += s3.x; aB.w += s3.y;
            *(float4*)&aggS[w][(fo << 3) + 0] = aA;
            *(float4*)&aggS[w][(fo << 3) + 4] = aB;
        }
        __builtin_amdgcn_sched_barrier(0);   // pin LDS write->read order

        // transform: out[lane] = b + dn * sum_k agg[k] * Ws[k][lane]
        float acc = 0.f;
        #pragma unroll
        for (int k0 = 0; k0 < 64; k0 += 4) {
            float4 a4 = *(const float4*)&aggS[w][k0];   // broadcast (free)
            acc += a4.x * Ws[k0 + 0][lane] + a4.y * Ws[k0 + 1][lane]
                 + a4.z * Ws[k0 + 2][lane] + a4.w * Ws[k0 + 3][lane];
        }
        float dn = rsqrtf((float)n + 1.0f);
        float o = bcol + dn * acc;
        o = (o > 0.f) ? o : expm1f(o);
        out[(size_t)node * (3 * D) + col_off + lane] = o;      // coalesced 256B
        if (write_next)
            mnext[((size_t)node << 6) + lane] = __float2half_rn(dn * o);
    }
}

extern "C" void kernel_launch(void* const* d_in, const int* in_sizes, int n_in,
                              void* d_out, int out_size, void* d_ws, size_t ws_size,
                              hipStream_t stream) {
    const float* x   = (const float*)d_in[0];
    const int*   ei  = (const int*)d_in[1];
    const int*   src = ei;
    const int*   dst = ei + N_EDGES;
    const float* W[3] = {(const float*)d_in[2], (const float*)d_in[4], (const float*)d_in[6]};
    const float* b[3] = {(const float*)d_in[3], (const float*)d_in[5], (const float*)d_in[7]};
    float* out = (float*)d_out;

    // workspace layout (m buffers 16B-aligned for uint4 reads)
    char* ws = (char*)d_ws;
    unsigned* binned = (unsigned*)ws;            ws += (size_t)NB * CAP_B * 4;
    int*    bcur   = (int*)ws;                   ws += 256 * 4;
    int*    cnt    = (int*)ws;                   ws += N_NODES * 4;
    int*    csr    = (int*)ws;                   ws += (size_t)N_NODES * SLOT_CAP * 4;
    __half* m0     = (__half*)ws;                ws += (size_t)N_NODES * D * 2;
    __half* m1     = (__half*)ws;

    // CSR build + first-layer message pack
    k_zero<<<1, 256, 0, stream>>>(bcur);
    k_binA<<<BINA_BLOCKS, 256, 0, stream>>>(src, dst, bcur, binned);
    k_binB<<<NB, 256, 0, stream>>>(bcur, binned, csr, cnt, x, m0);

    __half* mp = m0;
    __half* mn = m1;
    for (int l = 0; l < 3; ++l) {
        k_layer<<<LAYER_BLOCKS, 256, 0, stream>>>(
            (const uint4*)mp, csr, cnt, W[l], b[l], out, l * D, mn, (l < 2) ? 1 : 0);
        __half* t = mp; mp = mn; mn = t;
    }
}